// Round 9
// baseline (603.701 us; speedup 1.0000x reference)
//
#include <hip/hip_runtime.h>
#include <math.h>

#define N_NODES 100000
#define S1 50
#define S2 10
#define HID 128
#define NT 16          // nodes per block in enc2_mlp

// transposed fp64 weight sizes
#define W2_ELEMS   (128 * 128)     // Wt2d[k][o]
#define WA_ELEMS   (129 * 128)     // Wtad[k][o], k=128 row = remaining-space col
#define WB_ELEMS   (128 * 64)      // Wtbd[k][o]
#define PAD_ELEMS  (W2_ELEMS + WA_ELEMS + WB_ELEMS)   // 41088

// ---------------- kernel 1: agg1 (fp64) fused with weight transpose+fp64-convert
__global__ __launch_bounds__(256) void prep_kernel(
    const float* __restrict__ feat, const int* __restrict__ neigh1,
    const float* __restrict__ W2, const float* __restrict__ w_a,
    const float* __restrict__ w_b,
    double* __restrict__ agg1d, double* __restrict__ wt)
{
    if (blockIdx.x >= 25000) {   // tail blocks: build transposed fp64 weights
        int i = (blockIdx.x - 25000) * 256 + threadIdx.x;
        if (i < W2_ELEMS) {
            int k = i >> 7, o = i & 127;
            wt[i] = (double)W2[o * 128 + k];
        } else if (i < W2_ELEMS + WA_ELEMS) {
            int j = i - W2_ELEMS;
            int k = j >> 7, o = j & 127;
            wt[i] = (double)w_a[o * 129 + k];
        } else if (i < PAD_ELEMS) {
            int j = i - W2_ELEMS - WA_ELEMS;
            int k = j >> 6, o = j & 63;
            wt[i] = (double)w_b[o * 128 + k];
        }
        return;
    }
    const int wid  = threadIdx.x >> 6;
    const int lane = threadIdx.x & 63;
    const int n = blockIdx.x * 4 + wid;
    if (n >= N_NODES) return;

    double f0 = 0.0, f1 = 0.0, f2 = 0.0;
    if (lane < S1) {
        int j = neigh1[n * S1 + lane];
        f0 = (double)feat[j * 3 + 0];
        f1 = (double)feat[j * 3 + 1];
        f2 = (double)feat[j * 3 + 2];
    } else if (lane == S1) {
        f0 = (double)feat[n * 3 + 0];
        f1 = (double)feat[n * 3 + 1];
        f2 = (double)feat[n * 3 + 2];
    }
    #pragma unroll
    for (int off = 32; off > 0; off >>= 1) {
        f0 += __shfl_down(f0, off);
        f1 += __shfl_down(f1, off);
        f2 += __shfl_down(f2, off);
    }
    if (lane == 0) {
        agg1d[n * 3 + 0] = f0 / 51.0;
        agg1d[n * 3 + 1] = f1 / 51.0;
        agg1d[n * 3 + 2] = f2 / 51.0;
    }
}

// ---------------- kernel 2: enc2 + MLP + score, fp64.
// 256 threads (4 waves), 16 nodes/block, 32 KB LDS -> 4-5 blocks/CU (16-20 waves).
// Weights: fp64, TRANSPOSED [k][o] in workspace -> double2 loads at [k][2tq]
// are lane-consecutive (coalesced, 1 line per 4 lanes), zero cvts in hot loop.
// Per thread: outs {2tq, 2tq+1, 64+2tq, 64+2tq+1} x nodes {2ng, 2ng+1}.
// Activation LDS reads are 32-lane broadcasts; all LDS writes lane-consecutive.
__global__ __launch_bounds__(256, 4) void enc2_mlp_kernel(
    const int* __restrict__ nodes, const int* __restrict__ neigh2,
    const double* __restrict__ agg1d,
    const float* __restrict__ W1, const double* __restrict__ wt,
    const float* __restrict__ b_a, const float* __restrict__ b_b,
    const float* __restrict__ w_c, const float* __restrict__ b_c,
    const int* __restrict__ psz, const int* __restrict__ npe,
    double* __restrict__ scoresd)
{
    __shared__ __align__(16) double sA[NT * HID];   // 16 KB
    __shared__ __align__(16) double sB[NT * HID];   // 16 KB; overlay sG in ph0-1
    double* sG = sB;                                // 176 rows x 4 doubles (3 used)

    const double* __restrict__ Wt2 = wt;
    const double* __restrict__ Wta = wt + W2_ELEMS;
    const double* __restrict__ Wtb = wt + W2_ELEMS + WA_ELEMS;

    const int tid  = threadIdx.x;
    const int base = blockIdx.x * NT;               // 6250*16 == 100000

    // ---- phase 0: gather 11 agg1 rows per node into sG
    if (tid < NT * (S2 + 1)) {
        int t = tid;
        int ns = t / 11, j = t - ns * 11;
        int node = nodes[base + ns];
        int src  = (j == 0) ? node : neigh2[node * S2 + (j - 1)];
        sG[t * 4 + 0] = agg1d[src * 3 + 0];
        sG[t * 4 + 1] = agg1d[src * 3 + 1];
        sG[t * 4 + 2] = agg1d[src * 3 + 2];
    }
    __syncthreads();

    // ---- phase 1: agg2[ns][t] = mean_j relu(W1[t].row_j) -> sA[ns*128+t]
    // t lane-consecutive -> conflict-free stride-1 writes; sG reads broadcast.
    {
        const int t  = tid & 127;
        const int h8 = (tid >> 7) * 8;              // half handles 8 nodes
        const double wx = (double)W1[t * 3 + 0];
        const double wy = (double)W1[t * 3 + 1];
        const double wz = (double)W1[t * 3 + 2];
        #pragma unroll
        for (int s = 0; s < 8; s++) {
            int ns = h8 + s;
            double acc = 0.0;
            #pragma unroll
            for (int j = 0; j < 11; j++) {
                const double* g = &sG[(ns * 11 + j) * 4];
                acc += fmax(wx * g[0] + wy * g[1] + wz * g[2], 0.0);
            }
            sA[ns * 128 + t] = acc / 11.0;
        }
    }
    __syncthreads();

    const int tq = tid & 31;    // out pair base 2tq (and +64)
    const int ng = tid >> 5;    // 0..7 -> nodes {2ng, 2ng+1}
    const int o0 = 2 * tq;

    // ---- phase 2: emb = relu(W2 @ agg2) : sA -> sB
    {
        double acc[4][2] = {};
        const double* a0 = &sA[(2 * ng) * 128];
        const double* a1 = &sA[(2 * ng + 1) * 128];
        const double* w0 = &Wt2[o0];
        const double* w1 = &Wt2[64 + o0];
        #pragma unroll 4
        for (int kp = 0; kp < 64; kp++) {
            double2 av0 = *(const double2*)&a0[2 * kp];
            double2 av1 = *(const double2*)&a1[2 * kp];
            double2 we0 = *(const double2*)&w0[(2 * kp) * 128];
            double2 wo0 = *(const double2*)&w0[(2 * kp + 1) * 128];
            double2 we1 = *(const double2*)&w1[(2 * kp) * 128];
            double2 wo1 = *(const double2*)&w1[(2 * kp + 1) * 128];
            acc[0][0] += we0.x * av0.x + wo0.x * av0.y;
            acc[0][1] += we0.x * av1.x + wo0.x * av1.y;
            acc[1][0] += we0.y * av0.x + wo0.y * av0.y;
            acc[1][1] += we0.y * av1.x + wo0.y * av1.y;
            acc[2][0] += we1.x * av0.x + wo1.x * av0.y;
            acc[2][1] += we1.x * av1.x + wo1.x * av1.y;
            acc[3][0] += we1.y * av0.x + wo1.y * av0.y;
            acc[3][1] += we1.y * av1.x + wo1.y * av1.y;
        }
        #pragma unroll
        for (int j = 0; j < 2; j++) {
            double2 lo = { fmax(acc[0][j], 0.0), fmax(acc[1][j], 0.0) };
            double2 hi = { fmax(acc[2][j], 0.0), fmax(acc[3][j], 0.0) };
            *(double2*)&sB[(2 * ng + j) * 128 + o0]      = lo;
            *(double2*)&sB[(2 * ng + j) * 128 + 64 + o0] = hi;
        }
    }
    __syncthreads();

    // ---- phase 3: xa = relu(w_a[:,:128] @ emb + w_a[:,128]*rem + b_a) : sB -> sA
    {
        double acc[4][2] = {};
        const double* a0 = &sB[(2 * ng) * 128];
        const double* a1 = &sB[(2 * ng + 1) * 128];
        const double* w0 = &Wta[o0];
        const double* w1 = &Wta[64 + o0];
        #pragma unroll 4
        for (int kp = 0; kp < 64; kp++) {
            double2 av0 = *(const double2*)&a0[2 * kp];
            double2 av1 = *(const double2*)&a1[2 * kp];
            double2 we0 = *(const double2*)&w0[(2 * kp) * 128];
            double2 wo0 = *(const double2*)&w0[(2 * kp + 1) * 128];
            double2 we1 = *(const double2*)&w1[(2 * kp) * 128];
            double2 wo1 = *(const double2*)&w1[(2 * kp + 1) * 128];
            acc[0][0] += we0.x * av0.x + wo0.x * av0.y;
            acc[0][1] += we0.x * av1.x + wo0.x * av1.y;
            acc[1][0] += we0.y * av0.x + wo0.y * av0.y;
            acc[1][1] += we0.y * av1.x + wo0.y * av1.y;
            acc[2][0] += we1.x * av0.x + wo1.x * av0.y;
            acc[2][1] += we1.x * av1.x + wo1.x * av1.y;
            acc[3][0] += we1.y * av0.x + wo1.y * av0.y;
            acc[3][1] += we1.y * av1.x + wo1.y * av1.y;
        }
        const double rem = (double)(psz[0] - npe[0]);
        double2 re_lo = *(const double2*)&Wta[128 * 128 + o0];
        double2 re_hi = *(const double2*)&Wta[128 * 128 + 64 + o0];
        double add0 = re_lo.x * rem + (double)b_a[o0];
        double add1 = re_lo.y * rem + (double)b_a[o0 + 1];
        double add2 = re_hi.x * rem + (double)b_a[64 + o0];
        double add3 = re_hi.y * rem + (double)b_a[64 + o0 + 1];
        #pragma unroll
        for (int j = 0; j < 2; j++) {
            double2 lo = { fmax(acc[0][j] + add0, 0.0), fmax(acc[1][j] + add1, 0.0) };
            double2 hi = { fmax(acc[2][j] + add2, 0.0), fmax(acc[3][j] + add3, 0.0) };
            *(double2*)&sA[(2 * ng + j) * 128 + o0]      = lo;
            *(double2*)&sA[(2 * ng + j) * 128 + 64 + o0] = hi;
        }
    }
    __syncthreads();

    // ---- phase 4: xb = relu(w_b @ xa + b_b) : sA -> sB[n*64+o], o<64
    {
        double acc[2][2] = {};
        const double* a0 = &sA[(2 * ng) * 128];
        const double* a1 = &sA[(2 * ng + 1) * 128];
        const double* w0 = &Wtb[o0];
        #pragma unroll 4
        for (int kp = 0; kp < 64; kp++) {
            double2 av0 = *(const double2*)&a0[2 * kp];
            double2 av1 = *(const double2*)&a1[2 * kp];
            double2 we = *(const double2*)&w0[(2 * kp) * 64];
            double2 wo = *(const double2*)&w0[(2 * kp + 1) * 64];
            acc[0][0] += we.x * av0.x + wo.x * av0.y;
            acc[0][1] += we.x * av1.x + wo.x * av1.y;
            acc[1][0] += we.y * av0.x + wo.y * av0.y;
            acc[1][1] += we.y * av1.x + wo.y * av1.y;
        }
        double bb0 = (double)b_b[o0], bb1 = (double)b_b[o0 + 1];
        #pragma unroll
        for (int j = 0; j < 2; j++) {
            double2 v = { fmax(acc[0][j] + bb0, 0.0), fmax(acc[1][j] + bb1, 0.0) };
            *(double2*)&sB[(2 * ng + j) * 64 + o0] = v;
        }
    }
    __syncthreads();

    // ---- phase 5: score = w_c . xb + b_c   (16 threads per node)
    {
        const int j16 = tid & 15, ns = tid >> 4;
        double v = 0.0;
        #pragma unroll
        for (int r = 0; r < 4; r++)
            v += (double)w_c[j16 + 16 * r] * sB[ns * 64 + j16 + 16 * r];
        v += __shfl_down(v, 8);
        v += __shfl_down(v, 4);
        v += __shfl_down(v, 2);
        v += __shfl_down(v, 1);
        if (j16 == 0)
            scoresd[base + ns] = v + (double)b_c[0];
    }
}

// ---------------- softmax chain: 3 kernels ----------------
__global__ __launch_bounds__(256) void reduce_max_kernel(
    const double* __restrict__ s, double* __restrict__ pmax)
{
    __shared__ double red[4];
    const int tid = threadIdx.x;
    double m = -INFINITY;
    for (int i = blockIdx.x * 256 + tid; i < N_NODES; i += gridDim.x * 256)
        m = fmax(m, s[i]);
    #pragma unroll
    for (int off = 32; off > 0; off >>= 1) m = fmax(m, __shfl_down(m, off));
    if ((tid & 63) == 0) red[tid >> 6] = m;
    __syncthreads();
    if (tid == 0)
        pmax[blockIdx.x] = fmax(fmax(red[0], red[1]), fmax(red[2], red[3]));
}

__global__ __launch_bounds__(256) void exp_sum_kernel(
    double* __restrict__ s, const double* __restrict__ pmax,
    double* __restrict__ psum)
{
    __shared__ double red[4];
    const int tid = threadIdx.x;
    double m = pmax[tid];
    #pragma unroll
    for (int off = 32; off > 0; off >>= 1) m = fmax(m, __shfl_down(m, off));
    if ((tid & 63) == 0) red[tid >> 6] = m;
    __syncthreads();
    m = fmax(fmax(red[0], red[1]), fmax(red[2], red[3]));
    __syncthreads();

    double acc = 0.0;
    for (int i = blockIdx.x * 256 + tid; i < N_NODES; i += gridDim.x * 256) {
        double e = exp(s[i] - m);
        s[i] = e;
        acc += e;
    }
    #pragma unroll
    for (int off = 32; off > 0; off >>= 1) acc += __shfl_down(acc, off);
    if ((tid & 63) == 0) red[tid >> 6] = acc;
    __syncthreads();
    if (tid == 0)
        psum[blockIdx.x] = (red[0] + red[1]) + (red[2] + red[3]);
}

__global__ __launch_bounds__(256) void scale_kernel(
    const double* __restrict__ e, const double* __restrict__ psum,
    float* __restrict__ out)
{
    __shared__ double red[4];
    const int tid = threadIdx.x;
    double acc = psum[tid];
    #pragma unroll
    for (int off = 32; off > 0; off >>= 1) acc += __shfl_down(acc, off);
    if ((tid & 63) == 0) red[tid >> 6] = acc;
    __syncthreads();
    const double invS = 1.0 / ((red[0] + red[1]) + (red[2] + red[3]));
    const int i = blockIdx.x * 256 + tid;
    if (i < N_NODES) out[i] = (float)(e[i] * invS);
}

// ---------------- launch ----------------
extern "C" void kernel_launch(void* const* d_in, const int* in_sizes, int n_in,
                              void* d_out, int out_size, void* d_ws, size_t ws_size,
                              hipStream_t stream)
{
    const int*   nodes = (const int*)  d_in[0];
    const float* feat  = (const float*)d_in[1];
    const int*   n1    = (const int*)  d_in[2];
    const int*   n2    = (const int*)  d_in[3];
    const float* W1    = (const float*)d_in[4];
    const float* W2    = (const float*)d_in[5];
    const float* w_a   = (const float*)d_in[6];
    const float* b_a   = (const float*)d_in[7];
    const float* w_b   = (const float*)d_in[8];
    const float* b_b   = (const float*)d_in[9];
    const float* w_c   = (const float*)d_in[10];
    const float* b_c   = (const float*)d_in[11];
    const int*   psz   = (const int*)  d_in[12];
    const int*   npe   = (const int*)  d_in[13];
    float* out = (float*)d_out;

    double* agg1d   = (double*)d_ws;                       // 300000
    double* scoresd = agg1d + (size_t)N_NODES * 3;         // 100000
    double* pmax    = scoresd + N_NODES;                   // 256
    double* psum    = pmax + 256;                          // 256
    double* wt      = psum + 256;                          // PAD_ELEMS fp64

    const int pad_blocks = (PAD_ELEMS + 255) / 256;        // 161
    prep_kernel<<<25000 + pad_blocks, 256, 0, stream>>>(
        feat, n1, W2, w_a, w_b, agg1d, wt);
    enc2_mlp_kernel<<<N_NODES / NT, 256, 0, stream>>>(
        nodes, n2, agg1d, W1, wt, b_a, b_b, w_c, b_c, psz, npe, scoresd);
    reduce_max_kernel<<<256, 256, 0, stream>>>(scoresd, pmax);
    exp_sum_kernel<<<256, 256, 0, stream>>>(scoresd, pmax, psum);
    scale_kernel<<<(N_NODES + 255) / 256, 256, 0, stream>>>(scoresd, psum, out);
}

// Round 10
// 408.402 us; speedup vs baseline: 1.4782x; 1.4782x over previous
//
#include <hip/hip_runtime.h>
#include <math.h>

#define N_NODES 100000
#define S1 50
#define S2 10
#define HID 128
#define NT 32          // nodes per block in enc2_mlp
#define AST 34         // act row stride in doubles ([k][n] rows, 16B-aligned, 2-way free)

// transposed fp64 weight sizes (same layout as r9 — verified correct)
#define W2_ELEMS   (128 * 128)     // Wt2[k][o]
#define WA_ELEMS   (129 * 128)     // Wta[k][o], k=128 row = remaining-space col
#define WB_ELEMS   (128 * 64)      // Wtb[k][o]
#define PAD_ELEMS  (W2_ELEMS + WA_ELEMS + WB_ELEMS)   // 41088

// ---------------- kernel 1: agg1 (fp64) fused with weight transpose+fp64-convert
__global__ __launch_bounds__(256) void prep_kernel(
    const float* __restrict__ feat, const int* __restrict__ neigh1,
    const float* __restrict__ W2, const float* __restrict__ w_a,
    const float* __restrict__ w_b,
    double* __restrict__ agg1d, double* __restrict__ wt)
{
    if (blockIdx.x >= 25000) {   // tail blocks: build transposed fp64 weights
        int i = (blockIdx.x - 25000) * 256 + threadIdx.x;
        if (i < W2_ELEMS) {
            int k = i >> 7, o = i & 127;
            wt[i] = (double)W2[o * 128 + k];
        } else if (i < W2_ELEMS + WA_ELEMS) {
            int j = i - W2_ELEMS;
            int k = j >> 7, o = j & 127;
            wt[i] = (double)w_a[o * 129 + k];
        } else if (i < PAD_ELEMS) {
            int j = i - W2_ELEMS - WA_ELEMS;
            int k = j >> 6, o = j & 63;
            wt[i] = (double)w_b[o * 128 + k];
        }
        return;
    }
    const int wid  = threadIdx.x >> 6;
    const int lane = threadIdx.x & 63;
    const int n = blockIdx.x * 4 + wid;
    if (n >= N_NODES) return;

    double f0 = 0.0, f1 = 0.0, f2 = 0.0;
    if (lane < S1) {
        int j = neigh1[n * S1 + lane];
        f0 = (double)feat[j * 3 + 0];
        f1 = (double)feat[j * 3 + 1];
        f2 = (double)feat[j * 3 + 2];
    } else if (lane == S1) {
        f0 = (double)feat[n * 3 + 0];
        f1 = (double)feat[n * 3 + 1];
        f2 = (double)feat[n * 3 + 2];
    }
    #pragma unroll
    for (int off = 32; off > 0; off >>= 1) {
        f0 += __shfl_down(f0, off);
        f1 += __shfl_down(f1, off);
        f2 += __shfl_down(f2, off);
    }
    if (lane == 0) {
        agg1d[n * 3 + 0] = f0 / 51.0;
        agg1d[n * 3 + 1] = f1 / 51.0;
        agg1d[n * 3 + 2] = f2 / 51.0;
    }
}

// ---------------- kernel 2: enc2 + MLP + score, fp64.
// 256 threads (4 waves), 32 nodes/block, 3125 blocks. Acts in LDS as [k][n]
// (stride 34). Wave w owns outs [32w,32w+32): each weight element read from
// L2 EXACTLY ONCE per block per phase (was 4-8x -> the r8/r9 L2-BW wall).
// Per thread: 4 outs {o0,o0+1,o0+16,o0+17} x 4 nodes {4m..4m+3}; per k:
// 2 global weight double2 + 2 LDS act double2 -> 16 fp64 FMAs.
__global__ __launch_bounds__(256, 2) void enc2_mlp_kernel(
    const int* __restrict__ nodes, const int* __restrict__ neigh2,
    const double* __restrict__ agg1d,
    const float* __restrict__ W1, const double* __restrict__ wt,
    const float* __restrict__ b_a, const float* __restrict__ b_b,
    const float* __restrict__ w_c, const float* __restrict__ b_c,
    const int* __restrict__ psz, const int* __restrict__ npe,
    double* __restrict__ scoresd)
{
    __shared__ __align__(16) double sA[HID * AST];  // 34816 B, [k][n]
    __shared__ __align__(16) double sB[HID * AST];  // 34816 B; overlay sG in ph0-1
    double* sG = sB;                                // 352 rows x 4 doubles (3 used)

    const double* __restrict__ Wt2 = wt;
    const double* __restrict__ Wta = wt + W2_ELEMS;
    const double* __restrict__ Wtb = wt + W2_ELEMS + WA_ELEMS;

    const int tid  = threadIdx.x;
    const int base = blockIdx.x * NT;               // 3125*32 == 100000

    // ---- phase 0: gather 11 agg1 rows per node into sG (352 items)
    for (int t = tid; t < NT * (S2 + 1); t += 256) {
        int ns = t / 11, j = t - ns * 11;
        int node = nodes[base + ns];
        int src  = (j == 0) ? node : neigh2[node * S2 + (j - 1)];
        sG[t * 4 + 0] = agg1d[src * 3 + 0];
        sG[t * 4 + 1] = agg1d[src * 3 + 1];
        sG[t * 4 + 2] = agg1d[src * 3 + 2];
    }
    __syncthreads();

    // ---- phase 1: agg2[t][n] = mean_j relu(W1[t].row_j) -> sA[t*AST+n]
    // one node per thread; its 33 doubles hoisted to registers
    {
        const int n = tid & 31;
        double g0[11], g1[11], g2[11];
        #pragma unroll
        for (int j = 0; j < 11; j++) {
            g0[j] = sG[(n * 11 + j) * 4 + 0];
            g1[j] = sG[(n * 11 + j) * 4 + 1];
            g2[j] = sG[(n * 11 + j) * 4 + 2];
        }
        #pragma unroll
        for (int s = 0; s < 16; s++) {
            int t = (tid >> 5) + 8 * s;             // covers 0..127
            double wx = (double)W1[t * 3 + 0];
            double wy = (double)W1[t * 3 + 1];
            double wz = (double)W1[t * 3 + 2];
            double acc = 0.0;
            #pragma unroll
            for (int j = 0; j < 11; j++)
                acc += fmax(wx * g0[j] + wy * g1[j] + wz * g2[j], 0.0);
            sA[t * AST + n] = acc / 11.0;
        }
    }
    __syncthreads();   // sG(=sB) reads done; sA complete

    const int lane = tid & 63;
    const int wave = tid >> 6;        // 0..3
    const int oq   = lane & 7;        // out-pair selector
    const int m    = lane >> 3;       // 0..7 -> nodes 4m..4m+3
    const int n0   = 4 * m;
    const int o0   = 32 * wave + 2 * oq;   // outs o0,o0+1,o0+16,o0+17

    // ---- phase 2: emb = relu(W2 @ agg2) : sA -> sB
    {
        double acc[4][4] = {};
        const double* __restrict__ wk = &Wt2[o0];
        const double* __restrict__ ak = &sA[n0];
        #pragma unroll 4
        for (int k = 0; k < 128; k++) {
            double2 wlo = *(const double2*)&wk[k * 128];
            double2 whi = *(const double2*)&wk[k * 128 + 16];
            double2 a01 = *(const double2*)&ak[k * AST];
            double2 a23 = *(const double2*)&ak[k * AST + 2];
            acc[0][0] += wlo.x * a01.x; acc[0][1] += wlo.x * a01.y;
            acc[0][2] += wlo.x * a23.x; acc[0][3] += wlo.x * a23.y;
            acc[1][0] += wlo.y * a01.x; acc[1][1] += wlo.y * a01.y;
            acc[1][2] += wlo.y * a23.x; acc[1][3] += wlo.y * a23.y;
            acc[2][0] += whi.x * a01.x; acc[2][1] += whi.x * a01.y;
            acc[2][2] += whi.x * a23.x; acc[2][3] += whi.x * a23.y;
            acc[3][0] += whi.y * a01.x; acc[3][1] += whi.y * a01.y;
            acc[3][2] += whi.y * a23.x; acc[3][3] += whi.y * a23.y;
        }
        #pragma unroll
        for (int i = 0; i < 4; i++) {
            int o = o0 + (i & 1) + (i >> 1) * 16;
            int ii = (i & 1) ? 1 : 0; (void)ii;
        }
        const int om[4] = { o0, o0 + 1, o0 + 16, o0 + 17 };
        #pragma unroll
        for (int i = 0; i < 4; i++) {
            double2 lo = { fmax(acc[i][0], 0.0), fmax(acc[i][1], 0.0) };
            double2 hi = { fmax(acc[i][2], 0.0), fmax(acc[i][3], 0.0) };
            *(double2*)&sB[om[i] * AST + n0]     = lo;
            *(double2*)&sB[om[i] * AST + n0 + 2] = hi;
        }
    }
    __syncthreads();

    // ---- phase 3: xa = relu(w_a[:,:128] @ emb + w_a[:,128]*rem + b_a) : sB -> sA
    {
        double acc[4][4] = {};
        const double* __restrict__ wk = &Wta[o0];
        const double* __restrict__ ak = &sB[n0];
        #pragma unroll 4
        for (int k = 0; k < 128; k++) {
            double2 wlo = *(const double2*)&wk[k * 128];
            double2 whi = *(const double2*)&wk[k * 128 + 16];
            double2 a01 = *(const double2*)&ak[k * AST];
            double2 a23 = *(const double2*)&ak[k * AST + 2];
            acc[0][0] += wlo.x * a01.x; acc[0][1] += wlo.x * a01.y;
            acc[0][2] += wlo.x * a23.x; acc[0][3] += wlo.x * a23.y;
            acc[1][0] += wlo.y * a01.x; acc[1][1] += wlo.y * a01.y;
            acc[1][2] += wlo.y * a23.x; acc[1][3] += wlo.y * a23.y;
            acc[2][0] += whi.x * a01.x; acc[2][1] += whi.x * a01.y;
            acc[2][2] += whi.x * a23.x; acc[2][3] += whi.x * a23.y;
            acc[3][0] += whi.y * a01.x; acc[3][1] += whi.y * a01.y;
            acc[3][2] += whi.y * a23.x; acc[3][3] += whi.y * a23.y;
        }
        const double rem = (double)(psz[0] - npe[0]);
        double2 rlo = *(const double2*)&Wta[128 * 128 + o0];
        double2 rhi = *(const double2*)&Wta[128 * 128 + o0 + 16];
        const int om[4] = { o0, o0 + 1, o0 + 16, o0 + 17 };
        const double ad[4] = {
            rlo.x * rem + (double)b_a[om[0]],
            rlo.y * rem + (double)b_a[om[1]],
            rhi.x * rem + (double)b_a[om[2]],
            rhi.y * rem + (double)b_a[om[3]] };
        #pragma unroll
        for (int i = 0; i < 4; i++) {
            double2 lo = { fmax(acc[i][0] + ad[i], 0.0), fmax(acc[i][1] + ad[i], 0.0) };
            double2 hi = { fmax(acc[i][2] + ad[i], 0.0), fmax(acc[i][3] + ad[i], 0.0) };
            *(double2*)&sA[om[i] * AST + n0]     = lo;
            *(double2*)&sA[om[i] * AST + n0 + 2] = hi;
        }
    }
    __syncthreads();

    // ---- phase 4: xb = relu(w_b @ xa + b_b) : sA -> sB  (64 outs; wave w: [16w,16w+16))
    {
        const int o4 = 16 * wave + 2 * oq;    // outs o4, o4+1
        double acc[2][4] = {};
        const double* __restrict__ wk = &Wtb[o4];
        const double* __restrict__ ak = &sA[n0];
        #pragma unroll 4
        for (int k = 0; k < 128; k++) {
            double2 w = *(const double2*)&wk[k * 64];
            double2 a01 = *(const double2*)&ak[k * AST];
            double2 a23 = *(const double2*)&ak[k * AST + 2];
            acc[0][0] += w.x * a01.x; acc[0][1] += w.x * a01.y;
            acc[0][2] += w.x * a23.x; acc[0][3] += w.x * a23.y;
            acc[1][0] += w.y * a01.x; acc[1][1] += w.y * a01.y;
            acc[1][2] += w.y * a23.x; acc[1][3] += w.y * a23.y;
        }
        #pragma unroll
        for (int i = 0; i < 2; i++) {
            int o = o4 + i;
            double bb = (double)b_b[o];
            double2 lo = { fmax(acc[i][0] + bb, 0.0), fmax(acc[i][1] + bb, 0.0) };
            double2 hi = { fmax(acc[i][2] + bb, 0.0), fmax(acc[i][3] + bb, 0.0) };
            *(double2*)&sB[o * AST + n0]     = lo;
            *(double2*)&sB[o * AST + n0 + 2] = hi;
        }
    }
    __syncthreads();

    // ---- phase 5: score = w_c . xb + b_c   (8 threads per node, 32 nodes)
    {
        const int j8 = tid & 7, ns = tid >> 3;
        double v = 0.0;
        #pragma unroll
        for (int r = 0; r < 8; r++)
            v += (double)w_c[j8 + 8 * r] * sB[(j8 + 8 * r) * AST + ns];
        v += __shfl_down(v, 4);
        v += __shfl_down(v, 2);
        v += __shfl_down(v, 1);
        if (j8 == 0)
            scoresd[base + ns] = v + (double)b_c[0];
    }
}

// ---------------- softmax chain: 3 kernels ----------------
__global__ __launch_bounds__(256) void reduce_max_kernel(
    const double* __restrict__ s, double* __restrict__ pmax)
{
    __shared__ double red[4];
    const int tid = threadIdx.x;
    double m = -INFINITY;
    for (int i = blockIdx.x * 256 + tid; i < N_NODES; i += gridDim.x * 256)
        m = fmax(m, s[i]);
    #pragma unroll
    for (int off = 32; off > 0; off >>= 1) m = fmax(m, __shfl_down(m, off));
    if ((tid & 63) == 0) red[tid >> 6] = m;
    __syncthreads();
    if (tid == 0)
        pmax[blockIdx.x] = fmax(fmax(red[0], red[1]), fmax(red[2], red[3]));
}

__global__ __launch_bounds__(256) void exp_sum_kernel(
    double* __restrict__ s, const double* __restrict__ pmax,
    double* __restrict__ psum)
{
    __shared__ double red[4];
    const int tid = threadIdx.x;
    double m = pmax[tid];
    #pragma unroll
    for (int off = 32; off > 0; off >>= 1) m = fmax(m, __shfl_down(m, off));
    if ((tid & 63) == 0) red[tid >> 6] = m;
    __syncthreads();
    m = fmax(fmax(red[0], red[1]), fmax(red[2], red[3]));
    __syncthreads();

    double acc = 0.0;
    for (int i = blockIdx.x * 256 + tid; i < N_NODES; i += gridDim.x * 256) {
        double e = exp(s[i] - m);
        s[i] = e;
        acc += e;
    }
    #pragma unroll
    for (int off = 32; off > 0; off >>= 1) acc += __shfl_down(acc, off);
    if ((tid & 63) == 0) red[tid >> 6] = acc;
    __syncthreads();
    if (tid == 0)
        psum[blockIdx.x] = (red[0] + red[1]) + (red[2] + red[3]);
}

__global__ __launch_bounds__(256) void scale_kernel(
    const double* __restrict__ e, const double* __restrict__ psum,
    float* __restrict__ out)
{
    __shared__ double red[4];
    const int tid = threadIdx.x;
    double acc = psum[tid];
    #pragma unroll
    for (int off = 32; off > 0; off >>= 1) acc += __shfl_down(acc, off);
    if ((tid & 63) == 0) red[tid >> 6] = acc;
    __syncthreads();
    const double invS = 1.0 / ((red[0] + red[1]) + (red[2] + red[3]));
    const int i = blockIdx.x * 256 + tid;
    if (i < N_NODES) out[i] = (float)(e[i] * invS);
}

// ---------------- launch ----------------
extern "C" void kernel_launch(void* const* d_in, const int* in_sizes, int n_in,
                              void* d_out, int out_size, void* d_ws, size_t ws_size,
                              hipStream_t stream)
{
    const int*   nodes = (const int*)  d_in[0];
    const float* feat  = (const float*)d_in[1];
    const int*   n1    = (const int*)  d_in[2];
    const int*   n2    = (const int*)  d_in[3];
    const float* W1    = (const float*)d_in[4];
    const float* W2    = (const float*)d_in[5];
    const float* w_a   = (const float*)d_in[6];
    const float* b_a   = (const float*)d_in[7];
    const float* w_b   = (const float*)d_in[8];
    const float* b_b   = (const float*)d_in[9];
    const float* w_c   = (const float*)d_in[10];
    const float* b_c   = (const float*)d_in[11];
    const int*   psz   = (const int*)  d_in[12];
    const int*   npe   = (const int*)  d_in[13];
    float* out = (float*)d_out;

    double* agg1d   = (double*)d_ws;                       // 300000
    double* scoresd = agg1d + (size_t)N_NODES * 3;         // 100000
    double* pmax    = scoresd + N_NODES;                   // 256
    double* psum    = pmax + 256;                          // 256
    double* wt      = psum + 256;                          // PAD_ELEMS fp64

    const int pad_blocks = (PAD_ELEMS + 255) / 256;        // 161
    prep_kernel<<<25000 + pad_blocks, 256, 0, stream>>>(
        feat, n1, W2, w_a, w_b, agg1d, wt);
    enc2_mlp_kernel<<<N_NODES / NT, 256, 0, stream>>>(
        nodes, n2, agg1d, W1, wt, b_a, b_b, w_c, b_c, psz, npe, scoresd);
    reduce_max_kernel<<<256, 256, 0, stream>>>(scoresd, pmax);
    exp_sum_kernel<<<256, 256, 0, stream>>>(scoresd, pmax, psum);
    scale_kernel<<<(N_NODES + 255) / 256, 256, 0, stream>>>(scoresd, psum, out);
}